// Round 1
// baseline (365.456 us; speedup 1.0000x reference)
//
#include <hip/hip_runtime.h>
#include <math.h>

// Problem constants (B,C,H,W = 32,16,64,64; K=3; out=64; N_BASIS=6; +1 silu feature)
#define Bsz 32
#define Cc  16
#define Hh  64
#define Ww  64
#define HO  62
#define WO  62
#define OD  64
#define ND  144          // C*K*K
#define NF  7            // 6 spline bases + 1 silu feature

#define TW_OUT 32        // output cols per block
#define TW_IN  34        // input cols needed (32 + K - 1)
#define TW_PAD 36        // padded (multiple of 4 floats -> 16B-aligned rows)

__device__ __forceinline__ void load10(const float* p, float f[10]) {
    float4 a = *(const float4*)(p);
    float4 b = *(const float4*)(p + 4);
    float2 c = *(const float2*)(p + 8);
    f[0]=a.x; f[1]=a.y; f[2]=a.z; f[3]=a.w;
    f[4]=b.x; f[5]=b.y; f[6]=b.z; f[7]=b.w;
    f[8]=c.x; f[9]=c.y;
}

// Pack fused weights: wf[(d*7+n)*64+o] = coef[d][o][n]*scale_sp[d][o] (n<6), scale_base[d][o] (n==6)
__global__ __launch_bounds__(256) void kan_prep(const float* __restrict__ coef,
                                                const float* __restrict__ sbase,
                                                const float* __restrict__ ssp,
                                                float* __restrict__ wf) {
    int idx = blockIdx.x * 256 + threadIdx.x;
    if (idx >= ND * NF * OD) return;
    int o = idx & 63;
    int t = idx >> 6;
    int n = t % NF;
    int d = t / NF;
    float v;
    if (n < 6) v = coef[d * 384 + o * 6 + n] * ssp[d * 64 + o];
    else       v = sbase[d * 64 + o];
    wf[idx] = v;
}

template<bool FUSED>
__global__ __launch_bounds__(256) void kan_main(const float* __restrict__ x,
                                                const float* __restrict__ coef,
                                                const float* __restrict__ sbase,
                                                const float* __restrict__ ssp,
                                                const float* __restrict__ wf,
                                                float* __restrict__ out) {
    __shared__ float sfeat[Cc * 3 * NF * TW_PAD];   // 12096 floats = 48.4 KB

    const int wt   = blockIdx.x;       // 0..1
    const int hrow = blockIdx.y;       // 0..61
    const int b    = blockIdx.z;       // 0..31
    const int w0   = wt * TW_OUT;
    const int tid  = threadIdx.x;

    const float hstep = 2.0f / 3.0f;   // uniform knot spacing, matches f32 ref
    float T[10];
    #pragma unroll
    for (int j = 0; j < 10; ++j) T[j] = (float)(j - 3) * hstep - 1.0f;

    // ---- Stage features: per x element compute 6 bases + silu into LDS ----
    for (int i = tid; i < Cc * 3 * TW_IN; i += 256) {
        int wloc = i % TW_IN;
        int tmp  = i / TW_IN;
        int r    = tmp % 3;
        int c    = tmp / 3;
        int col  = w0 + wloc; if (col > Ww - 1) col = Ww - 1;   // clamp; results discarded
        float xv = x[((b * Cc + c) * Hh + (hrow + r)) * Ww + col];

        float bb[9];
        #pragma unroll
        for (int j = 0; j < 9; ++j) bb[j] = (xv >= T[j] && xv < T[j + 1]) ? 1.0f : 0.0f;
        #pragma unroll
        for (int d = 1; d <= 3; ++d) {
            #pragma unroll
            for (int j = 0; j + d < 9; ++j) {
                float left  = (xv - T[j]) / (T[j + d] - T[j]) * bb[j];
                float right = (T[j + d + 1] - xv) / (T[j + d + 1] - T[j + 1]) * bb[j + 1];
                bb[j] = left + right;
            }
        }
        float sig = 1.0f / (1.0f + expf(-xv));

        int base = ((c * 3 + r) * NF) * TW_PAD + wloc;
        #pragma unroll
        for (int n = 0; n < 6; ++n) sfeat[base + n * TW_PAD] = bb[n];
        sfeat[base + 6 * TW_PAD] = xv * sig;
    }
    __syncthreads();

    // ---- Main accumulation: thread = (o, wq) over 8 consecutive w ----
    const int o  = tid & 63;
    const int wq = tid >> 6;           // 0..3
    float acc[8];
    #pragma unroll
    for (int p = 0; p < 8; ++p) acc[p] = 0.0f;

    for (int c = 0; c < Cc; ++c) {
        #pragma unroll
        for (int di = 0; di < 3; ++di) {
            const int d0 = c * 9 + di * 3;
            const float* frow = &sfeat[((c * 3 + di) * NF) * TW_PAD + wq * 8];
            if (FUSED) {
                #pragma unroll
                for (int n = 0; n < NF; ++n) {
                    float f[10]; load10(frow + n * TW_PAD, f);
                    #pragma unroll
                    for (int dj = 0; dj < 3; ++dj) {
                        float wgt = wf[((d0 + dj) * NF + n) * 64 + o];
                        #pragma unroll
                        for (int p = 0; p < 8; ++p) acc[p] = fmaf(f[p + dj], wgt, acc[p]);
                    }
                }
            } else {
                float ssp_[3], sb_[3];
                #pragma unroll
                for (int dj = 0; dj < 3; ++dj) {
                    ssp_[dj] = ssp[(d0 + dj) * 64 + o];
                    sb_[dj]  = sbase[(d0 + dj) * 64 + o];
                }
                {   // silu feature (n==6)
                    float f[10]; load10(frow + 6 * TW_PAD, f);
                    #pragma unroll
                    for (int dj = 0; dj < 3; ++dj)
                        #pragma unroll
                        for (int p = 0; p < 8; ++p) acc[p] = fmaf(f[p + dj], sb_[dj], acc[p]);
                }
                #pragma unroll
                for (int n = 0; n < 6; ++n) {
                    float f[10]; load10(frow + n * TW_PAD, f);
                    #pragma unroll
                    for (int dj = 0; dj < 3; ++dj) {
                        float wgt = coef[(d0 + dj) * 384 + o * 6 + n] * ssp_[dj];
                        #pragma unroll
                        for (int p = 0; p < 8; ++p) acc[p] = fmaf(f[p + dj], wgt, acc[p]);
                    }
                }
            }
        }
    }

    // ---- Transpose through LDS so global stores are w-contiguous ----
    __syncthreads();
    float* sout = sfeat;               // reuse; need 64*33 = 2112 floats
    #pragma unroll
    for (int p = 0; p < 8; ++p) sout[o * 33 + wq * 8 + p] = acc[p];
    __syncthreads();

    #pragma unroll
    for (int j = 0; j < 8; ++j) {
        int idx  = j * 256 + tid;      // 0..2047
        int oo   = idx >> 5;
        int wcol = idx & 31;
        int w    = w0 + wcol;
        if (w < WO) out[((b * OD + oo) * HO + hrow) * WO + w] = sout[oo * 33 + wcol];
    }
}

extern "C" void kernel_launch(void* const* d_in, const int* in_sizes, int n_in,
                              void* d_out, int out_size, void* d_ws, size_t ws_size,
                              hipStream_t stream) {
    (void)in_sizes; (void)n_in; (void)out_size;
    const float* x     = (const float*)d_in[0];
    const float* coef  = (const float*)d_in[1];
    const float* sbase = (const float*)d_in[2];
    const float* ssp   = (const float*)d_in[3];
    float* out = (float*)d_out;

    const size_t wf_bytes = (size_t)ND * NF * OD * sizeof(float);   // 258 KB
    dim3 grid(2, HO, Bsz);

    if (ws_size >= wf_bytes) {
        float* wf = (float*)d_ws;
        kan_prep<<<(ND * NF * OD + 255) / 256, 256, 0, stream>>>(coef, sbase, ssp, wf);
        kan_main<true><<<grid, 256, 0, stream>>>(x, coef, sbase, ssp, wf, out);
    } else {
        kan_main<false><<<grid, 256, 0, stream>>>(x, coef, sbase, ssp, nullptr, out);
    }
}

// Round 2
// 111.264 us; speedup vs baseline: 3.2846x; 3.2846x over previous
//
#include <hip/hip_runtime.h>
#include <math.h>

#define Bsz 32
#define Cc  16
#define Hh  64
#define Ww  64
#define HO  62
#define WO  62
#define OD  64
#define ND  144           // d = c*9 + di*3 + dj
#define NCHUNK 36         // K = 1152 = 36 chunks of 32 (4 d's per chunk)
#define FW  68            // feature row width (64 + shift pad, 16B-aligned stride)

using short8 = __attribute__((ext_vector_type(8))) short;
using f32x4  = __attribute__((ext_vector_type(4))) float;

__device__ __forceinline__ unsigned short f2bf(float f) {
    union { float f; unsigned u; } v; v.f = f;
    unsigned r = v.u + 0x7fff + ((v.u >> 16) & 1);   // round-to-nearest-even
    return (unsigned short)(r >> 16);
}
__device__ __forceinline__ float bf2f(unsigned short h) {
    union { unsigned u; float f; } v; v.u = ((unsigned)h) << 16; return v.f;
}

// ---- weight prep: wp[(d*64+o)*8+n] = n<6 ? coef[d][o][n]*ssp[d][o] : sbase[d][o] (bf16)
__global__ __launch_bounds__(256) void kan_prep(const float* __restrict__ coef,
                                                const float* __restrict__ sbase,
                                                const float* __restrict__ ssp,
                                                unsigned short* __restrict__ wp) {
    int idx = blockIdx.x * 256 + threadIdx.x;
    if (idx >= ND * OD * 8) return;
    int n = idx & 7, o = (idx >> 3) & 63, d = idx >> 9;
    float v = (n < 6) ? coef[(d * OD + o) * 6 + n] * ssp[d * OD + o] : sbase[d * OD + o];
    wp[idx] = f2bf(v);
}

// ---- main MFMA kernel: block = 128 thr (2 waves), 2 output rows, N=64, K=1152
__global__ __launch_bounds__(128) void kan_mfma(const float* __restrict__ x,
                                                const unsigned short* __restrict__ wp,
                                                float* __restrict__ out) {
    __shared__ uint4 feat[Cc * 4 * FW];   // 69,632 B

    const int rp   = blockIdx.x;          // output row pair 0..30
    const int b    = blockIdx.y;          // batch
    const int tid  = threadIdx.x;
    const int wid  = tid >> 6;            // wave 0..1 -> output row hrow0+wid
    const int lane = tid & 63;
    const int l15  = lane & 15;
    const int ks   = lane >> 4;           // k-segment 0..3 (d within chunk)
    const int hrow0 = rp * 2;

    // ---------- fill feature tile: closed-form uniform cubic B-spline ----------
    for (int i = tid; i < Cc * 4 * FW; i += 128) {
        int wl = i % FW;
        int cr = i / FW;
        int r = cr & 3, c = cr >> 2;
        int col = wl < Ww ? wl : Ww - 1;                 // pad cols clamp (discarded)
        float xv = x[((b * Cc + c) * Hh + hrow0 + r) * Ww + col];

        float xi = (xv + 3.0f) * 1.5f;                    // knot interval coordinate
        float fi = floorf(xi);
        int   ii = (int)fi;
        float u  = xi - fi;
        float u2 = u * u, u3 = u2 * u;
        float P0 = u3 * (1.0f / 6.0f);                            // Q(u)
        float P1 = (1.0f + 3.0f * u + 3.0f * u2 - 3.0f * u3) * (1.0f / 6.0f);
        float P2 = (4.0f - 6.0f * u2 + 3.0f * u3) * (1.0f / 6.0f);
        float om = 1.0f - u;
        float P3 = om * om * om * (1.0f / 6.0f);
        bool ok = (ii >= 0) && (ii <= 8);

        float bas[6];
        #pragma unroll
        for (int n = 0; n < 6; ++n) {
            int t = ii - n;
            float v = (t == 0) ? P0 : (t == 1) ? P1 : (t == 2) ? P2 : (t == 3) ? P3 : 0.0f;
            bas[n] = ok ? v : 0.0f;
        }
        float s   = xv / (1.0f + __expf(-xv));           // silu
        unsigned short sh = f2bf(s);
        unsigned short sl = f2bf(s - bf2f(sh));          // error-compensation term

        uint4 pk;
        pk.x = (unsigned)f2bf(bas[0]) | ((unsigned)f2bf(bas[1]) << 16);
        pk.y = (unsigned)f2bf(bas[2]) | ((unsigned)f2bf(bas[3]) << 16);
        pk.z = (unsigned)f2bf(bas[4]) | ((unsigned)f2bf(bas[5]) << 16);
        pk.w = (unsigned)sh | ((unsigned)sl << 16);
        feat[i] = pk;
    }
    __syncthreads();

    // ---------- K-loop: 36 chunks, dbuf regs, no barriers ----------
    f32x4 acc[4][4];
    #pragma unroll
    for (int rt = 0; rt < 4; ++rt)
        #pragma unroll
        for (int ct = 0; ct < 4; ++ct)
            acc[rt][ct] = (f32x4){0.f, 0.f, 0.f, 0.f};

    auto loadA = [&](int chunk, short8* A) {
        int d = chunk * 4 + ks;
        int c = (d * 57) >> 9;            // d/9
        int rem = d - c * 9;
        int di = (rem * 11) >> 5;         // rem/3
        int dj = rem - di * 3;
        const short8* ap = (const short8*)&feat[(c * 4 + wid + di) * FW + l15 + dj];
        A[0] = ap[0]; A[1] = ap[16]; A[2] = ap[32]; A[3] = ap[48];   // rt*16 w-shift
    };
    auto loadB = [&](int chunk, short8* Bf) {
        int d = chunk * 4 + ks;
        const short8* bp = (const short8*)wp + (d * 64 + l15);
        Bf[0] = bp[0]; Bf[1] = bp[16]; Bf[2] = bp[32]; Bf[3] = bp[48]; // ct*16 cols
    };

    short8 A0[4], B0[4], A1[4], B1[4];
    loadA(0, A0); loadB(0, B0);

    for (int cb = 0; cb < NCHUNK; cb += 2) {
        loadA(cb + 1, A1); loadB(cb + 1, B1);
        #pragma unroll
        for (int rt = 0; rt < 4; ++rt)
            #pragma unroll
            for (int ct = 0; ct < 4; ++ct)
                acc[rt][ct] = __builtin_amdgcn_mfma_f32_16x16x32_bf16(A0[rt], B0[ct], acc[rt][ct], 0, 0, 0);
        if (cb + 2 < NCHUNK) { loadA(cb + 2, A0); loadB(cb + 2, B0); }
        #pragma unroll
        for (int rt = 0; rt < 4; ++rt)
            #pragma unroll
            for (int ct = 0; ct < 4; ++ct)
                acc[rt][ct] = __builtin_amdgcn_mfma_f32_16x16x32_bf16(A1[rt], B1[ct], acc[rt][ct], 0, 0, 0);
    }

    // ---------- epilogue: transpose through LDS, coalesced stores ----------
    __syncthreads();                       // feature tile dead; reuse as sC
    float* sC = ((float*)feat) + wid * (OD * FW);
    #pragma unroll
    for (int rt = 0; rt < 4; ++rt)
        #pragma unroll
        for (int ct = 0; ct < 4; ++ct) {
            // lane holds rows w = rt*16 + ks*4 + r, col o = ct*16 + l15
            *(f32x4*)&sC[(ct * 16 + l15) * FW + rt * 16 + ks * 4] = acc[rt][ct];
        }

    const int orow = hrow0 + wid;
    for (int j = 0; j < OD; ++j) {
        float v = sC[j * FW + lane];
        if (lane < WO)
            out[((b * OD + j) * HO + orow) * WO + lane] = v;
    }
}

// ---------- fallback (no workspace): round-1 f32 VALU kernel, non-fused ----------
#define TW_OUT 32
#define TW_IN  34
#define TW_PAD 36
__device__ __forceinline__ void load10(const float* p, float f[10]) {
    float4 a = *(const float4*)(p);
    float4 b = *(const float4*)(p + 4);
    float2 c = *(const float2*)(p + 8);
    f[0]=a.x; f[1]=a.y; f[2]=a.z; f[3]=a.w;
    f[4]=b.x; f[5]=b.y; f[6]=b.z; f[7]=b.w;
    f[8]=c.x; f[9]=c.y;
}
__global__ __launch_bounds__(256) void kan_fb(const float* __restrict__ x,
                                              const float* __restrict__ coef,
                                              const float* __restrict__ sbase,
                                              const float* __restrict__ ssp,
                                              float* __restrict__ out) {
    __shared__ float sfeat[Cc * 3 * 7 * TW_PAD];
    const int wt = blockIdx.x, hrow = blockIdx.y, b = blockIdx.z;
    const int w0 = wt * TW_OUT, tid = threadIdx.x;
    const float hstep = 2.0f / 3.0f;
    float T[10];
    #pragma unroll
    for (int j = 0; j < 10; ++j) T[j] = (float)(j - 3) * hstep - 1.0f;
    for (int i = tid; i < Cc * 3 * TW_IN; i += 256) {
        int wloc = i % TW_IN, tmp = i / TW_IN, r = tmp % 3, c = tmp / 3;
        int col = w0 + wloc; if (col > Ww - 1) col = Ww - 1;
        float xv = x[((b * Cc + c) * Hh + (hrow + r)) * Ww + col];
        float bb[9];
        #pragma unroll
        for (int j = 0; j < 9; ++j) bb[j] = (xv >= T[j] && xv < T[j + 1]) ? 1.0f : 0.0f;
        #pragma unroll
        for (int d = 1; d <= 3; ++d)
            #pragma unroll
            for (int j = 0; j + d < 9; ++j) {
                float left  = (xv - T[j]) / (T[j + d] - T[j]) * bb[j];
                float right = (T[j + d + 1] - xv) / (T[j + d + 1] - T[j + 1]) * bb[j + 1];
                bb[j] = left + right;
            }
        float sig = 1.0f / (1.0f + expf(-xv));
        int base = ((c * 3 + r) * 7) * TW_PAD + wloc;
        #pragma unroll
        for (int n = 0; n < 6; ++n) sfeat[base + n * TW_PAD] = bb[n];
        sfeat[base + 6 * TW_PAD] = xv * sig;
    }
    __syncthreads();
    const int o = tid & 63, wq = tid >> 6;
    float acc[8];
    #pragma unroll
    for (int p = 0; p < 8; ++p) acc[p] = 0.0f;
    for (int c = 0; c < Cc; ++c)
        #pragma unroll
        for (int di = 0; di < 3; ++di) {
            const int d0 = c * 9 + di * 3;
            const float* frow = &sfeat[((c * 3 + di) * 7) * TW_PAD + wq * 8];
            float ssp_[3], sb_[3];
            #pragma unroll
            for (int dj = 0; dj < 3; ++dj) { ssp_[dj] = ssp[(d0+dj)*64+o]; sb_[dj] = sbase[(d0+dj)*64+o]; }
            { float f[10]; load10(frow + 6 * TW_PAD, f);
              #pragma unroll
              for (int dj = 0; dj < 3; ++dj)
                  #pragma unroll
                  for (int p = 0; p < 8; ++p) acc[p] = fmaf(f[p + dj], sb_[dj], acc[p]); }
            #pragma unroll
            for (int n = 0; n < 6; ++n) {
                float f[10]; load10(frow + n * TW_PAD, f);
                #pragma unroll
                for (int dj = 0; dj < 3; ++dj) {
                    float wgt = coef[(d0 + dj) * 384 + o * 6 + n] * ssp_[dj];
                    #pragma unroll
                    for (int p = 0; p < 8; ++p) acc[p] = fmaf(f[p + dj], wgt, acc[p]);
                }
            }
        }
    __syncthreads();
    float* sout = sfeat;
    #pragma unroll
    for (int p = 0; p < 8; ++p) sout[o * 33 + wq * 8 + p] = acc[p];
    __syncthreads();
    #pragma unroll
    for (int j = 0; j < 8; ++j) {
        int idx = j * 256 + tid, oo = idx >> 5, wcol = idx & 31, w = w0 + wcol;
        if (w < WO) out[((b * OD + oo) * HO + hrow) * WO + w] = sout[oo * 33 + wcol];
    }
}

extern "C" void kernel_launch(void* const* d_in, const int* in_sizes, int n_in,
                              void* d_out, int out_size, void* d_ws, size_t ws_size,
                              hipStream_t stream) {
    (void)in_sizes; (void)n_in; (void)out_size;
    const float* x     = (const float*)d_in[0];
    const float* coef  = (const float*)d_in[1];
    const float* sbase = (const float*)d_in[2];
    const float* ssp   = (const float*)d_in[3];
    float* out = (float*)d_out;

    const size_t wp_bytes = (size_t)ND * OD * 8 * sizeof(unsigned short);  // 147,456

    if (ws_size >= wp_bytes) {
        unsigned short* wp = (unsigned short*)d_ws;
        kan_prep<<<(ND * OD * 8 + 255) / 256, 256, 0, stream>>>(coef, sbase, ssp, wp);
        dim3 grid(HO / 2, Bsz);
        kan_mfma<<<grid, 128, 0, stream>>>(x, wp, out);
    } else {
        dim3 grid(2, HO, Bsz);
        kan_fb<<<grid, 256, 0, stream>>>(x, coef, sbase, ssp, out);
    }
}

// Round 3
// 48.286 us; speedup vs baseline: 7.5686x; 2.3043x over previous
//
#include <hip/hip_runtime.h>
#include <math.h>

#define Bsz 32
#define Cc  16
#define Hh  64
#define Ww  64
#define HO  62
#define WO  62
#define OD  64
#define ND  144           // d = c*9 + di*3 + dj
#define NCHUNK 36         // K = 1152 = 36 chunks of 32 (4 d's per chunk)
#define BSKEW 520         // ushorts per d-block in skewed B (1040 B: 1024 + 16B skew)
#define BSM_U16 77824     // 19*512*8 ushorts = 155,648 B LDS image (149,760 used + pad)

using short8 = __attribute__((ext_vector_type(8))) short;
using f32x4  = __attribute__((ext_vector_type(4))) float;

__device__ __forceinline__ unsigned short f2bf(float f) {
    union { float f; unsigned u; } v; v.f = f;
    unsigned r = v.u + 0x7fff + ((v.u >> 16) & 1);
    return (unsigned short)(r >> 16);
}
__device__ __forceinline__ float bf2f(unsigned short h) {
    union { unsigned u; float f; } v; v.u = ((unsigned)h) << 16; return v.f;
}

__device__ __forceinline__ uint4 feat_pack(float xv) {
    float xi = (xv + 3.0f) * 1.5f;
    float fi = floorf(xi);
    int   ii = (int)fi;
    float u  = xi - fi;
    float u2 = u * u, u3 = u2 * u;
    float P0 = u3 * (1.0f / 6.0f);
    float P1 = (1.0f + 3.0f * u + 3.0f * u2 - 3.0f * u3) * (1.0f / 6.0f);
    float P2 = (4.0f - 6.0f * u2 + 3.0f * u3) * (1.0f / 6.0f);
    float om = 1.0f - u;
    float P3 = om * om * om * (1.0f / 6.0f);
    bool ok = (ii >= 0) && (ii <= 8);
    float bas[6];
    #pragma unroll
    for (int n = 0; n < 6; ++n) {
        int t = ii - n;
        float v = (t == 0) ? P0 : (t == 1) ? P1 : (t == 2) ? P2 : (t == 3) ? P3 : 0.0f;
        bas[n] = ok ? v : 0.0f;
    }
    float s = xv / (1.0f + __expf(-xv));
    unsigned short sh = f2bf(s);
    unsigned short sl = f2bf(s - bf2f(sh));
    uint4 pk;
    pk.x = (unsigned)f2bf(bas[0]) | ((unsigned)f2bf(bas[1]) << 16);
    pk.y = (unsigned)f2bf(bas[2]) | ((unsigned)f2bf(bas[3]) << 16);
    pk.z = (unsigned)f2bf(bas[4]) | ((unsigned)f2bf(bas[5]) << 16);
    pk.w = (unsigned)sh | ((unsigned)sl << 16);
    return pk;
}

// ---- kernel 1: per-element features into global (33.5 MB) ----
__global__ __launch_bounds__(256) void kan_feat(const float* __restrict__ x,
                                                uint4* __restrict__ fg) {
    int base = blockIdx.x * 2048 + threadIdx.x;
    #pragma unroll
    for (int j = 0; j < 8; ++j) {
        int i = base + j * 256;
        fg[i] = feat_pack(x[i]);
    }
}

// ---- kernel 1b: skewed bf16 weights (LDS image) ----
__global__ __launch_bounds__(256) void kan_prep2(const float* __restrict__ coef,
                                                 const float* __restrict__ sbase,
                                                 const float* __restrict__ ssp,
                                                 unsigned short* __restrict__ wps) {
    int p = blockIdx.x * 256 + threadIdx.x;
    if (p >= BSM_U16) return;
    int dd  = p / BSKEW;
    int rem = p - dd * BSKEW;
    int o = rem >> 3, n = rem & 7;
    float v = 0.0f;
    if (dd < ND && rem < 512)
        v = (n < 6) ? coef[(dd * OD + o) * 6 + n] * ssp[dd * OD + o] : sbase[dd * OD + o];
    wps[p] = f2bf(v);
}

// ---- kernel 2: persistent-ish GEMM, B in LDS, wave = one output row ----
__global__ __launch_bounds__(512) void kan_gemm(const uint4* __restrict__ fg,
                                                const unsigned short* __restrict__ wps,
                                                float* __restrict__ out) {
    __shared__ unsigned short bsm[BSM_U16];   // 155,648 B

    const int tid  = threadIdx.x;
    const int bb   = blockIdx.x >> 3;
    const int h    = (blockIdx.x & 7) * 8 + (tid >> 6);
    const int wid  = tid >> 6;
    const int lane = tid & 63;
    const int l15  = lane & 15;
    const int ks   = lane >> 4;
    const bool alive = (h < HO);

    // stage B (global -> LDS), 9728 uint4, 19 exact iterations
    {
        const uint4* src = (const uint4*)wps;
        uint4* dst = (uint4*)bsm;
        #pragma unroll
        for (int it = 0; it < 19; ++it) dst[it * 512 + tid] = src[it * 512 + tid];
    }
    __syncthreads();

    f32x4 acc[4][4];
    #pragma unroll
    for (int rt = 0; rt < 4; ++rt)
        #pragma unroll
        for (int ct = 0; ct < 4; ++ct) acc[rt][ct] = (f32x4){0.f, 0.f, 0.f, 0.f};

    if (alive) {
        const unsigned short* bbase = bsm + ks * BSKEW + l15 * 8;

        auto loadA = [&](int cb, short8* A) {
            int dd  = cb * 4 + ks;
            int c   = (dd * 57) >> 9;         // dd/9
            int rem = dd - c * 9;
            int di  = (rem * 11) >> 5;        // rem/3
            int dj  = rem - di * 3;
            const short8* ap = (const short8*)fg + ((((bb * Cc + c) << 6) + h + di) << 6) + l15 + dj;
            A[0] = ap[0]; A[1] = ap[16]; A[2] = ap[32]; A[3] = ap[48];
        };
        auto loadB = [&](int cb, short8* Bf) {
            const short8* bp = (const short8*)(bbase + cb * 4 * BSKEW);
            Bf[0] = bp[0]; Bf[1] = bp[16]; Bf[2] = bp[32]; Bf[3] = bp[48];
        };

        short8 A0[4], B0[4], A1[4], B1[4];
        loadA(0, A0); loadB(0, B0);
        for (int cb = 0; cb < NCHUNK; cb += 2) {
            loadA(cb + 1, A1); loadB(cb + 1, B1);
            #pragma unroll
            for (int rt = 0; rt < 4; ++rt)
                #pragma unroll
                for (int ct = 0; ct < 4; ++ct)
                    acc[rt][ct] = __builtin_amdgcn_mfma_f32_16x16x32_bf16(A0[rt], B0[ct], acc[rt][ct], 0, 0, 0);
            if (cb + 2 < NCHUNK) { loadA(cb + 2, A0); loadB(cb + 2, B0); }
            #pragma unroll
            for (int rt = 0; rt < 4; ++rt)
                #pragma unroll
                for (int ct = 0; ct < 4; ++ct)
                    acc[rt][ct] = __builtin_amdgcn_mfma_f32_16x16x32_bf16(A1[rt], B1[ct], acc[rt][ct], 0, 0, 0);
        }
    }

    // epilogue: reuse B-LDS as per-wave transpose scratch (8 x 17,408 B = 139 KB)
    __syncthreads();
    if (alive) {
        float* sc = (float*)bsm + wid * (OD * 68);
        #pragma unroll
        for (int rt = 0; rt < 4; ++rt)
            #pragma unroll
            for (int ct = 0; ct < 4; ++ct)
                *(f32x4*)&sc[(ct * 16 + l15) * 68 + rt * 16 + ks * 4] = acc[rt][ct];
        // wave-internal barrier not needed beyond LDS dependency: all lanes of the
        // wave wrote, same wave reads; ds ops within a wave complete in order of waitcnt
        #pragma unroll 4
        for (int j = 0; j < OD; ++j) {
            float v = sc[j * 68 + lane];
            if (lane < WO) out[((bb * OD + j) * HO + h) * WO + lane] = v;
        }
    }
}

// =================== fallback path (round-2 kernels) ===================
#define FW 68
__global__ __launch_bounds__(256) void kan_prep(const float* __restrict__ coef,
                                                const float* __restrict__ sbase,
                                                const float* __restrict__ ssp,
                                                unsigned short* __restrict__ wp) {
    int idx = blockIdx.x * 256 + threadIdx.x;
    if (idx >= ND * OD * 8) return;
    int n = idx & 7, o = (idx >> 3) & 63, d = idx >> 9;
    float v = (n < 6) ? coef[(d * OD + o) * 6 + n] * ssp[d * OD + o] : sbase[d * OD + o];
    wp[idx] = f2bf(v);
}

__global__ __launch_bounds__(128) void kan_mfma(const float* __restrict__ x,
                                                const unsigned short* __restrict__ wp,
                                                float* __restrict__ out) {
    __shared__ uint4 feat[Cc * 4 * FW];
    const int rp = blockIdx.x, b = blockIdx.y, tid = threadIdx.x;
    const int wid = tid >> 6, lane = tid & 63, l15 = lane & 15, ks = lane >> 4;
    const int hrow0 = rp * 2;
    for (int i = tid; i < Cc * 4 * FW; i += 128) {
        int wl = i % FW, cr = i / FW, r = cr & 3, c = cr >> 2;
        int col = wl < Ww ? wl : Ww - 1;
        feat[i] = feat_pack(x[((b * Cc + c) * Hh + hrow0 + r) * Ww + col]);
    }
    __syncthreads();
    f32x4 acc[4][4];
    #pragma unroll
    for (int rt = 0; rt < 4; ++rt)
        #pragma unroll
        for (int ct = 0; ct < 4; ++ct) acc[rt][ct] = (f32x4){0.f, 0.f, 0.f, 0.f};
    auto loadA = [&](int chunk, short8* A) {
        int d = chunk * 4 + ks;
        int c = (d * 57) >> 9;
        int rem = d - c * 9;
        int di = (rem * 11) >> 5;
        int dj = rem - di * 3;
        const short8* ap = (const short8*)&feat[(c * 4 + wid + di) * FW + l15 + dj];
        A[0] = ap[0]; A[1] = ap[16]; A[2] = ap[32]; A[3] = ap[48];
    };
    auto loadB = [&](int chunk, short8* Bf) {
        int d = chunk * 4 + ks;
        const short8* bp = (const short8*)wp + (d * 64 + l15);
        Bf[0] = bp[0]; Bf[1] = bp[16]; Bf[2] = bp[32]; Bf[3] = bp[48];
    };
    short8 A0[4], B0[4], A1[4], B1[4];
    loadA(0, A0); loadB(0, B0);
    for (int cb = 0; cb < NCHUNK; cb += 2) {
        loadA(cb + 1, A1); loadB(cb + 1, B1);
        #pragma unroll
        for (int rt = 0; rt < 4; ++rt)
            #pragma unroll
            for (int ct = 0; ct < 4; ++ct)
                acc[rt][ct] = __builtin_amdgcn_mfma_f32_16x16x32_bf16(A0[rt], B0[ct], acc[rt][ct], 0, 0, 0);
        if (cb + 2 < NCHUNK) { loadA(cb + 2, A0); loadB(cb + 2, B0); }
        #pragma unroll
        for (int rt = 0; rt < 4; ++rt)
            #pragma unroll
            for (int ct = 0; ct < 4; ++ct)
                acc[rt][ct] = __builtin_amdgcn_mfma_f32_16x16x32_bf16(A1[rt], B1[ct], acc[rt][ct], 0, 0, 0);
    }
    __syncthreads();
    float* sC = ((float*)feat) + wid * (OD * FW);
    #pragma unroll
    for (int rt = 0; rt < 4; ++rt)
        #pragma unroll
        for (int ct = 0; ct < 4; ++ct)
            *(f32x4*)&sC[(ct * 16 + l15) * FW + rt * 16 + ks * 4] = acc[rt][ct];
    const int orow = hrow0 + wid;
    for (int j = 0; j < OD; ++j) {
        float v = sC[j * FW + lane];
        if (lane < WO) out[((b * OD + j) * HO + orow) * WO + lane] = v;
    }
}

extern "C" void kernel_launch(void* const* d_in, const int* in_sizes, int n_in,
                              void* d_out, int out_size, void* d_ws, size_t ws_size,
                              hipStream_t stream) {
    (void)in_sizes; (void)n_in; (void)out_size;
    const float* x     = (const float*)d_in[0];
    const float* coef  = (const float*)d_in[1];
    const float* sbase = (const float*)d_in[2];
    const float* ssp   = (const float*)d_in[3];
    float* out = (float*)d_out;

    const size_t wps_bytes  = (size_t)BSM_U16 * 2;                    // 155,648
    const size_t featg_bytes = (size_t)Bsz * Cc * Hh * Ww * 16;       // 33,554,432
    const size_t need = wps_bytes + featg_bytes + 64;

    if (ws_size >= need) {
        unsigned short* wps = (unsigned short*)d_ws;
        uint4* fg = (uint4*)((char*)d_ws + wps_bytes);
        kan_feat<<<1024, 256, 0, stream>>>(x, fg);
        kan_prep2<<<(BSM_U16 + 255) / 256, 256, 0, stream>>>(coef, sbase, ssp, wps);
        kan_gemm<<<256, 512, 0, stream>>>(fg, wps, out);
    } else if (ws_size >= (size_t)ND * OD * 8 * 2) {
        unsigned short* wp = (unsigned short*)d_ws;
        kan_prep<<<(ND * OD * 8 + 255) / 256, 256, 0, stream>>>(coef, sbase, ssp, wp);
        dim3 grid(HO / 2, Bsz);
        kan_mfma<<<grid, 128, 0, stream>>>(x, wp, out);
    }
}